// Round 14
// baseline (106.074 us; speedup 1.0000x reference)
//
#include <hip/hip_runtime.h>
#include <cstdint>
#include <cstddef>

// MemristorDense: y[b,o] = C * sum_i [ exp2(Ep*L + Wp) - exp2(En*L + Wn) ]
// L[b,i]=log2(2x), E=log2(n), W=log2(kG*|w|+G_MIN), C=0.5*maxw/(G_MAX-G_MIN).
// R14 (= R12/R13 resubmit; infra-burst precedent R6->R8): no LDS reduce
// (67.5KB pinned us at 4 waves/SIMD; R8 proved the loop runs issue-bound at
// 8 waves/SIMD). Each wave atomicAdds its 16 partial diffs directly.
// ZCH=16 -> 1024 blocks; no __shared__, no barriers in k_main. Bias row
// folded out exactly (i=1024: L=1 -> n*g, added by the s==0,z==0 wave).

#define B128 128
#define NIN  1024
#define NI   1025
#define NO   512
#define NJ   1024
#define GMIN 1.0e-5f
#define GSPAN (1.0e-3f - 1.0e-5f)
#define ZCH  16     // K-chunks over [0,1024)
#define CHUNK 64

__device__ __forceinline__ float flog2(float x) { return __builtin_amdgcn_logf(x); }
__device__ __forceinline__ float fexp2(float x) { return __builtin_amdgcn_exp2f(x); }

// Kernel 1 (grid 256 x 1024): zero out, LT[i][b]=1+log2(x[b][i]), block max -> bmax[256].
__global__ __launch_bounds__(1024) void k_prep(
    const float* __restrict__ x,
    const float* __restrict__ wp, const float* __restrict__ wn,
    const float* __restrict__ bp, const float* __restrict__ bn,
    float* __restrict__ LT, float* __restrict__ bmax, float* __restrict__ out)
{
    const int tid = blockIdx.x * 1024 + threadIdx.x;   // [0, 262144)

    if (tid < B128 * NO) out[tid] = 0.0f;

    if (tid < NI * B128) {
        int i = tid >> 7, b = tid & 127;
        float xv = (i < NIN) ? x[b * NIN + i] : 1.0f;
        LT[tid] = 1.0f + flog2(xv);                 // log2(2x); x=0 -> -inf (correct)
    }

    // NIN*NO = 524288 = 2 * 262144 exactly
    float m = fmaxf(fmaxf(__builtin_fabsf(wp[tid]), __builtin_fabsf(wn[tid])),
                    fmaxf(__builtin_fabsf(wp[tid + 262144]), __builtin_fabsf(wn[tid + 262144])));
    if (tid < NO) m = fmaxf(m, fmaxf(__builtin_fabsf(bp[tid]), __builtin_fabsf(bn[tid])));

    __shared__ float red[16];
    #pragma unroll
    for (int off = 32; off > 0; off >>= 1) m = fmaxf(m, __shfl_down(m, off, 64));
    if ((threadIdx.x & 63) == 0) red[threadIdx.x >> 6] = m;
    __syncthreads();
    if (threadIdx.x < 16) {
        m = red[threadIdx.x];
        #pragma unroll
        for (int off = 8; off > 0; off >>= 1) m = fmaxf(m, __shfl_down(m, off, 16));
        if (threadIdx.x == 0) bmax[blockIdx.x] = m;
    }
}

// Kernel 2: grid (8 o-tiles, 8 b-tiles, 16 K-chunks) x 512 threads (8 waves).
// 1024 blocks, zero LDS -> occupancy VGPR-limited (~5-8 waves/SIMD). Wave s
// handles i = z*64 + s + 8k, k in [0,8) -- exactly 8 steps, no bounds checks.
// 16 batches/wave; per step: 4 log2 + 32 exp2. Each wave atomicAdds its 16
// partial diffs per lane; the (s==0, z==0) wave also adds the exact bias term.
__global__ __launch_bounds__(512) void k_main(
    const float* __restrict__ nd,
    const float* __restrict__ wp, const float* __restrict__ wn,
    const float* __restrict__ bp, const float* __restrict__ bn,
    const float* __restrict__ LT, const float* __restrict__ bmax,
    float* __restrict__ out)
{
    const int lane = threadIdx.x & 63;
    const int s    = threadIdx.x >> 6;      // wave id [0,8)
    const int o    = (blockIdx.x << 6) + lane;
    const int b0   = blockIdx.y << 4;       // 16 batches per block

    // reduce 256 per-block maxima (redundant per wave; L2-hot)
    float m = fmaxf(fmaxf(bmax[lane], bmax[lane + 64]),
                    fmaxf(bmax[lane + 128], bmax[lane + 192]));
    #pragma unroll
    for (int off = 32; off > 0; off >>= 1) m = fmaxf(m, __shfl_down(m, off, 64));
    const float maxw = __shfl(m, 0, 64);
    const float kG = GSPAN / maxw;
    const float C  = 0.5f * maxw / GSPAN;

    const int i0 = blockIdx.z * CHUNK + s;   // this wave's first i

    const float* pnd = nd + (size_t)i0 * NJ + 2 * o;
    const float* pwp = wp + (size_t)i0 * NO + o;
    const float* pwn = wn + (size_t)i0 * NO + o;
    const float* pL  = LT + (size_t)i0 * B128 + b0;

    float accp[16], accn[16];
    #pragma unroll
    for (int k = 0; k < 16; ++k) { accp[k] = 0.0f; accn[k] = 0.0f; }

    // prologue loads for k=0
    float2 nv = *(const float2*)pnd;
    float wvp = *pwp;
    float wvn = *pwn;
    float4 La = *(const float4*)(pL);
    float4 Lb = *(const float4*)(pL + 4);
    float4 Lc = *(const float4*)(pL + 8);
    float4 Ld = *(const float4*)(pL + 12);

    #pragma unroll
    for (int k = 0; k < 7; ++k) {
        pnd += 8 * NJ; pwp += 8 * NO; pwn += 8 * NO; pL += 8 * B128;
        float2 nv_n = *(const float2*)pnd;
        float wp_n = *pwp;
        float wn_n = *pwn;
        float4 Lan = *(const float4*)(pL);
        float4 Lbn = *(const float4*)(pL + 4);
        float4 Lcn = *(const float4*)(pL + 8);
        float4 Ldn = *(const float4*)(pL + 12);

        const float Ep = flog2(nv.x);
        const float En = flog2(nv.y);
        const float Wp = flog2(__builtin_fmaf(kG, __builtin_fabsf(wvp), GMIN));
        const float Wn = flog2(__builtin_fmaf(kG, __builtin_fabsf(wvn), GMIN));

        const float Lv[16] = {La.x, La.y, La.z, La.w, Lb.x, Lb.y, Lb.z, Lb.w,
                              Lc.x, Lc.y, Lc.z, Lc.w, Ld.x, Ld.y, Ld.z, Ld.w};
        #pragma unroll
        for (int j = 0; j < 16; ++j) {
            accp[j] += fexp2(__builtin_fmaf(Ep, Lv[j], Wp));
            accn[j] += fexp2(__builtin_fmaf(En, Lv[j], Wn));
        }

        nv = nv_n; wvp = wp_n; wvn = wn_n;
        La = Lan; Lb = Lbn; Lc = Lcn; Ld = Ldn;
    }

    // last step (k=7), no prefetch
    {
        const float Ep = flog2(nv.x);
        const float En = flog2(nv.y);
        const float Wp = flog2(__builtin_fmaf(kG, __builtin_fabsf(wvp), GMIN));
        const float Wn = flog2(__builtin_fmaf(kG, __builtin_fabsf(wvn), GMIN));
        const float Lv[16] = {La.x, La.y, La.z, La.w, Lb.x, Lb.y, Lb.z, Lb.w,
                              Lc.x, Lc.y, Lc.z, Lc.w, Ld.x, Ld.y, Ld.z, Ld.w};
        #pragma unroll
        for (int j = 0; j < 16; ++j) {
            accp[j] += fexp2(__builtin_fmaf(Ep, Lv[j], Wp));
            accn[j] += fexp2(__builtin_fmaf(En, Lv[j], Wn));
        }
    }

    // bias row (i=1024): L=1 -> term = n*g (pure mul), added exactly once per
    // output element by the s==0 wave of the z==0 block.
    float bias = 0.0f;
    if (blockIdx.z == 0 && s == 0) {
        const float2 nb = *(const float2*)(nd + (size_t)NIN * NJ + 2 * o);
        const float gp = __builtin_fmaf(kG, __builtin_fabsf(bp[o]), GMIN);
        const float gn = __builtin_fmaf(kG, __builtin_fabsf(bn[o]), GMIN);
        bias = nb.x * gp - nb.y * gn;
    }

    // direct atomic epilogue: 16 adds per lane, no LDS, no barrier.
    float* pout = out + (size_t)b0 * NO + o;
    #pragma unroll
    for (int j = 0; j < 16; ++j) {
        unsafeAtomicAdd(pout + (size_t)j * NO, C * (accp[j] - accn[j] + bias));
    }
}

extern "C" void kernel_launch(void* const* d_in, const int* in_sizes, int n_in,
                              void* d_out, int out_size, void* d_ws, size_t ws_size,
                              hipStream_t stream)
{
    const float* x  = (const float*)d_in[0];
    const float* wp = (const float*)d_in[1];
    const float* wn = (const float*)d_in[2];
    const float* bp = (const float*)d_in[3];
    const float* bn = (const float*)d_in[4];
    const float* nd = (const float*)d_in[5];
    float* out = (float*)d_out;

    unsigned char* ws = (unsigned char*)d_ws;
    float* bmax = (float*)ws;                 // 256 floats
    float* LT   = (float*)(ws + 4096);        // 1025*128*4 = 524800 B

    k_prep<<<256, 1024, 0, stream>>>(x, wp, wn, bp, bn, LT, bmax, out);
    k_main<<<dim3(8, 8, ZCH), 512, 0, stream>>>(nd, wp, wn, bp, bn, LT, bmax, out);
}

// Round 15
// 92.116 us; speedup vs baseline: 1.1515x; 1.1515x over previous
//
#include <hip/hip_runtime.h>
#include <cstdint>
#include <cstddef>

// MemristorDense: y[b,o] = C * sum_i [ exp2(Ep*L + Wp) - exp2(En*L + Wn) ]
// L[b,i]=log2(2x), E=log2(n), W=log2(kG*|w|+G_MIN), C=0.5*maxw/(G_MAX-G_MIN).
// R15: occupancy is VGPR-bound (>64 VGPR -> 4 waves/SIMD). bpw=8 fits ~58
// VGPR -> launch_bounds(512,8) -> 8 waves/SIMD (R8 proved 8 waves run
// issue-bound). Keep R11's cheap epilogue: LDS diff-reduce (18.4KB, 0.5M
// atomics total). Bias row folded out exactly (i=1024: L=1 -> n*g).

#define B128 128
#define NIN  1024
#define NI   1025
#define NO   512
#define NJ   1024
#define GMIN 1.0e-5f
#define GSPAN (1.0e-3f - 1.0e-5f)
#define ZCH  8      // K-chunks over [0,1024)
#define CHUNK 128

__device__ __forceinline__ float flog2(float x) { return __builtin_amdgcn_logf(x); }
__device__ __forceinline__ float fexp2(float x) { return __builtin_amdgcn_exp2f(x); }

// Kernel 1 (grid 256 x 1024): zero out, LT[i][b]=1+log2(x[b][i]), block max -> bmax[256].
__global__ __launch_bounds__(1024) void k_prep(
    const float* __restrict__ x,
    const float* __restrict__ wp, const float* __restrict__ wn,
    const float* __restrict__ bp, const float* __restrict__ bn,
    float* __restrict__ LT, float* __restrict__ bmax, float* __restrict__ out)
{
    const int tid = blockIdx.x * 1024 + threadIdx.x;   // [0, 262144)

    if (tid < B128 * NO) out[tid] = 0.0f;

    if (tid < NI * B128) {
        int i = tid >> 7, b = tid & 127;
        float xv = (i < NIN) ? x[b * NIN + i] : 1.0f;
        LT[tid] = 1.0f + flog2(xv);                 // log2(2x); x=0 -> -inf (correct)
    }

    // NIN*NO = 524288 = 2 * 262144 exactly
    float m = fmaxf(fmaxf(__builtin_fabsf(wp[tid]), __builtin_fabsf(wn[tid])),
                    fmaxf(__builtin_fabsf(wp[tid + 262144]), __builtin_fabsf(wn[tid + 262144])));
    if (tid < NO) m = fmaxf(m, fmaxf(__builtin_fabsf(bp[tid]), __builtin_fabsf(bn[tid])));

    __shared__ float red[16];
    #pragma unroll
    for (int off = 32; off > 0; off >>= 1) m = fmaxf(m, __shfl_down(m, off, 64));
    if ((threadIdx.x & 63) == 0) red[threadIdx.x >> 6] = m;
    __syncthreads();
    if (threadIdx.x < 16) {
        m = red[threadIdx.x];
        #pragma unroll
        for (int off = 8; off > 0; off >>= 1) m = fmaxf(m, __shfl_down(m, off, 16));
        if (threadIdx.x == 0) bmax[blockIdx.x] = m;
    }
}

// Kernel 2: grid (8 o-tiles, 16 b-tiles, 8 K-chunks) x 512 threads (8 waves).
// 1024 blocks = 4/CU. Wave s: i = z*128 + s + 8k, k in [0,16) -- 16 steps,
// no bounds checks. 8 batches/wave (16 acc VGPRs; target <=64 total for
// 8 waves/SIMD via launch_bounds(512,8)). Per step: 4 log2 + 16 exp2.
// Epilogue: LDS diff-reduce (stride 9, 18.4KB), 1 atomicAdd per thread.
__global__ __launch_bounds__(512, 8) void k_main(
    const float* __restrict__ nd,
    const float* __restrict__ wp, const float* __restrict__ wn,
    const float* __restrict__ bp, const float* __restrict__ bn,
    const float* __restrict__ LT, const float* __restrict__ bmax,
    float* __restrict__ out)
{
    const int lane = threadIdx.x & 63;
    const int s    = threadIdx.x >> 6;      // wave id = K-split [0,8)
    const int o    = (blockIdx.x << 6) + lane;
    const int b0   = blockIdx.y << 3;       // 8 batches per block

    // reduce 256 per-block maxima (redundant per wave; L2-hot)
    float m = fmaxf(fmaxf(bmax[lane], bmax[lane + 64]),
                    fmaxf(bmax[lane + 128], bmax[lane + 192]));
    #pragma unroll
    for (int off = 32; off > 0; off >>= 1) m = fmaxf(m, __shfl_down(m, off, 64));
    const float maxw = __shfl(m, 0, 64);
    const float kG = GSPAN / maxw;
    const float C  = 0.5f * maxw / GSPAN;

    const int i0 = blockIdx.z * CHUNK + s;   // this wave's first i

    const float* pnd = nd + (size_t)i0 * NJ + 2 * o;
    const float* pwp = wp + (size_t)i0 * NO + o;
    const float* pwn = wn + (size_t)i0 * NO + o;
    const float* pL  = LT + (size_t)i0 * B128 + b0;

    float accp[8], accn[8];
    #pragma unroll
    for (int k = 0; k < 8; ++k) { accp[k] = 0.0f; accn[k] = 0.0f; }

    // prologue loads for k=0
    float2 nv = *(const float2*)pnd;
    float wvp = *pwp;
    float wvn = *pwn;
    float4 La = *(const float4*)(pL);
    float4 Lb = *(const float4*)(pL + 4);

    #pragma unroll 3
    for (int k = 0; k < 15; ++k) {
        pnd += 8 * NJ; pwp += 8 * NO; pwn += 8 * NO; pL += 8 * B128;
        float2 nv_n = *(const float2*)pnd;
        float wp_n = *pwp;
        float wn_n = *pwn;
        float4 Lan = *(const float4*)(pL);
        float4 Lbn = *(const float4*)(pL + 4);

        const float Ep = flog2(nv.x);
        const float En = flog2(nv.y);
        const float Wp = flog2(__builtin_fmaf(kG, __builtin_fabsf(wvp), GMIN));
        const float Wn = flog2(__builtin_fmaf(kG, __builtin_fabsf(wvn), GMIN));

        const float Lv[8] = {La.x, La.y, La.z, La.w, Lb.x, Lb.y, Lb.z, Lb.w};
        #pragma unroll
        for (int j = 0; j < 8; ++j) {
            accp[j] += fexp2(__builtin_fmaf(Ep, Lv[j], Wp));
            accn[j] += fexp2(__builtin_fmaf(En, Lv[j], Wn));
        }

        nv = nv_n; wvp = wp_n; wvn = wn_n;
        La = Lan; Lb = Lbn;
    }

    // last step (k=15), no prefetch
    {
        const float Ep = flog2(nv.x);
        const float En = flog2(nv.y);
        const float Wp = flog2(__builtin_fmaf(kG, __builtin_fabsf(wvp), GMIN));
        const float Wn = flog2(__builtin_fmaf(kG, __builtin_fabsf(wvn), GMIN));
        const float Lv[8] = {La.x, La.y, La.z, La.w, Lb.x, Lb.y, Lb.z, Lb.w};
        #pragma unroll
        for (int j = 0; j < 8; ++j) {
            accp[j] += fexp2(__builtin_fmaf(Ep, Lv[j], Wp));
            accn[j] += fexp2(__builtin_fmaf(En, Lv[j], Wn));
        }
    }

    // LDS diff-reduce across the 8 waves. Row stride 9 floats -> conflict-free.
    __shared__ float lds[8 * 64 * 9];   // 18432 B
    {
        const int base = (s * 64 + lane) * 9;
        #pragma unroll
        for (int j = 0; j < 8; ++j) lds[base + j] = accp[j] - accn[j];
    }
    __syncthreads();

    // 512 threads: one output each. thread t -> (o-lane = t&63, b = t>>6).
    {
        const int l = threadIdx.x & 63;
        const int b = threadIdx.x >> 6;       // [0,8)
        float sum = 0.0f;
        #pragma unroll
        for (int w = 0; w < 8; ++w) sum += lds[(w * 64 + l) * 9 + b];

        // bias row (i=1024): L=1 -> term = n*g (pure mul), once per output,
        // added by the z==0 block that owns this (b-tile, o-tile).
        if (blockIdx.z == 0) {
            const int oo = (blockIdx.x << 6) + l;
            const float2 nb = *(const float2*)(nd + (size_t)NIN * NJ + 2 * oo);
            const float gp = __builtin_fmaf(kG, __builtin_fabsf(bp[oo]), GMIN);
            const float gn = __builtin_fmaf(kG, __builtin_fabsf(bn[oo]), GMIN);
            sum += nb.x * gp - nb.y * gn;
        }
        unsafeAtomicAdd(out + (size_t)(b0 + b) * NO + (blockIdx.x << 6) + l, C * sum);
    }
}

extern "C" void kernel_launch(void* const* d_in, const int* in_sizes, int n_in,
                              void* d_out, int out_size, void* d_ws, size_t ws_size,
                              hipStream_t stream)
{
    const float* x  = (const float*)d_in[0];
    const float* wp = (const float*)d_in[1];
    const float* wn = (const float*)d_in[2];
    const float* bp = (const float*)d_in[3];
    const float* bn = (const float*)d_in[4];
    const float* nd = (const float*)d_in[5];
    float* out = (float*)d_out;

    unsigned char* ws = (unsigned char*)d_ws;
    float* bmax = (float*)ws;                 // 256 floats
    float* LT   = (float*)(ws + 4096);        // 1025*128*4 = 524800 B

    k_prep<<<256, 1024, 0, stream>>>(x, wp, wn, bp, bn, LT, bmax, out);
    k_main<<<dim3(8, 16, ZCH), 512, 0, stream>>>(nd, wp, wn, bp, bn, LT, bmax, out);
}

// Round 17
// 90.065 us; speedup vs baseline: 1.1777x; 1.0228x over previous
//
#include <hip/hip_runtime.h>
#include <cstdint>
#include <cstddef>

// MemristorDense: y[b,o] = C * sum_i [ exp2(Ep*L + Wp) - exp2(En*L + Wn) ]
// L[b,i]=log2(2x), E=log2(n), W=log2(kG*|w|+G_MIN), C=0.5*maxw/(G_MAX-G_MIN).
// R17 (= R16 resubmit; infra burst precedent R6->R8, R12->R14): LT row is
// wave-uniform -> force SGPR address (readfirstlane) -> s_load_dwordx16,
// cutting VMEM instrs per step 7 -> 3 (nd float2, wp, wn) and freeing ~32
// VGPRs. bpw=16, ZCH=8, 512 blocks x 8 waves, diff-store LDS epilogue.

#define B128 128
#define NIN  1024
#define NI   1025
#define NO   512
#define NJ   1024
#define GMIN 1.0e-5f
#define GSPAN (1.0e-3f - 1.0e-5f)
#define ZCH  8      // K-chunks over [0,1024)
#define CHUNK 128

__device__ __forceinline__ float flog2(float x) { return __builtin_amdgcn_logf(x); }
__device__ __forceinline__ float fexp2(float x) { return __builtin_amdgcn_exp2f(x); }

// Kernel 1 (grid 256 x 1024): zero out, LT[i][b]=1+log2(x[b][i]), block max -> bmax[256].
__global__ __launch_bounds__(1024) void k_prep(
    const float* __restrict__ x,
    const float* __restrict__ wp, const float* __restrict__ wn,
    const float* __restrict__ bp, const float* __restrict__ bn,
    float* __restrict__ LT, float* __restrict__ bmax, float* __restrict__ out)
{
    const int tid = blockIdx.x * 1024 + threadIdx.x;   // [0, 262144)

    if (tid < B128 * NO) out[tid] = 0.0f;

    if (tid < NI * B128) {
        int i = tid >> 7, b = tid & 127;
        float xv = (i < NIN) ? x[b * NIN + i] : 1.0f;
        LT[tid] = 1.0f + flog2(xv);                 // log2(2x); x=0 -> -inf (correct)
    }

    // NIN*NO = 524288 = 2 * 262144 exactly
    float m = fmaxf(fmaxf(__builtin_fabsf(wp[tid]), __builtin_fabsf(wn[tid])),
                    fmaxf(__builtin_fabsf(wp[tid + 262144]), __builtin_fabsf(wn[tid + 262144])));
    if (tid < NO) m = fmaxf(m, fmaxf(__builtin_fabsf(bp[tid]), __builtin_fabsf(bn[tid])));

    __shared__ float red[16];
    #pragma unroll
    for (int off = 32; off > 0; off >>= 1) m = fmaxf(m, __shfl_down(m, off, 64));
    if ((threadIdx.x & 63) == 0) red[threadIdx.x >> 6] = m;
    __syncthreads();
    if (threadIdx.x < 16) {
        m = red[threadIdx.x];
        #pragma unroll
        for (int off = 8; off > 0; off >>= 1) m = fmaxf(m, __shfl_down(m, off, 16));
        if (threadIdx.x == 0) bmax[blockIdx.x] = m;
    }
}

// Kernel 2: grid (8 o-tiles, 8 b-tiles, 8 K-chunks) x 512 threads (8 waves).
// 512 blocks. Wave s: i = z*128 + s + 8k, k in [0,16). 16 batches/wave.
// LT row via wave-uniform s_load (SMEM pipe, SGPR result); only 3 VMEM
// instrs per step. Per step: 4 log2 + 32 exp2. LDS diff-reduce epilogue.
__global__ __launch_bounds__(512) void k_main(
    const float* __restrict__ nd,
    const float* __restrict__ wp, const float* __restrict__ wn,
    const float* __restrict__ bp, const float* __restrict__ bn,
    const float* __restrict__ LT, const float* __restrict__ bmax,
    float* __restrict__ out)
{
    const int lane = threadIdx.x & 63;
    const int s    = __builtin_amdgcn_readfirstlane(threadIdx.x >> 6);  // wave id [0,8)
    const int o    = (blockIdx.x << 6) + lane;
    const int b0   = blockIdx.y << 4;       // 16 batches per block (wave-uniform)

    // reduce 256 per-block maxima (redundant per wave; L2-hot)
    float m = fmaxf(fmaxf(bmax[lane], bmax[lane + 64]),
                    fmaxf(bmax[lane + 128], bmax[lane + 192]));
    #pragma unroll
    for (int off = 32; off > 0; off >>= 1) m = fmaxf(m, __shfl_down(m, off, 64));
    const float maxw = __shfl(m, 0, 64);
    const float kG = GSPAN / maxw;
    const float C  = 0.5f * maxw / GSPAN;

    const int i0 = blockIdx.z * CHUNK + s;   // this wave's first i (uniform)

    const float* pnd = nd + (size_t)i0 * NJ + 2 * o;
    const float* pwp = wp + (size_t)i0 * NO + o;
    const float* pwn = wn + (size_t)i0 * NO + o;
    const float* pL  = LT + (size_t)i0 * B128 + b0;   // wave-uniform address

    float accp[16], accn[16];
    #pragma unroll
    for (int k = 0; k < 16; ++k) { accp[k] = 0.0f; accn[k] = 0.0f; }

    // prologue loads for k=0
    float2 nv = *(const float2*)pnd;
    float wvp = *pwp;
    float wvn = *pwn;
    float Lv[16];
    #pragma unroll
    for (int j = 0; j < 16; ++j) Lv[j] = pL[j];   // uniform -> s_load_dwordx16

    #pragma unroll 2
    for (int k = 0; k < 15; ++k) {
        pnd += 8 * NJ; pwp += 8 * NO; pwn += 8 * NO; pL += 8 * B128;
        float2 nv_n = *(const float2*)pnd;
        float wp_n = *pwp;
        float wn_n = *pwn;
        float Lv_n[16];
        #pragma unroll
        for (int j = 0; j < 16; ++j) Lv_n[j] = pL[j];   // s_load for step k+1

        const float Ep = flog2(nv.x);
        const float En = flog2(nv.y);
        const float Wp = flog2(__builtin_fmaf(kG, __builtin_fabsf(wvp), GMIN));
        const float Wn = flog2(__builtin_fmaf(kG, __builtin_fabsf(wvn), GMIN));

        #pragma unroll
        for (int j = 0; j < 16; ++j) {
            accp[j] += fexp2(__builtin_fmaf(Ep, Lv[j], Wp));
            accn[j] += fexp2(__builtin_fmaf(En, Lv[j], Wn));
        }

        nv = nv_n; wvp = wp_n; wvn = wn_n;
        #pragma unroll
        for (int j = 0; j < 16; ++j) Lv[j] = Lv_n[j];
    }

    // last step (k=15), no prefetch
    {
        const float Ep = flog2(nv.x);
        const float En = flog2(nv.y);
        const float Wp = flog2(__builtin_fmaf(kG, __builtin_fabsf(wvp), GMIN));
        const float Wn = flog2(__builtin_fmaf(kG, __builtin_fabsf(wvn), GMIN));
        #pragma unroll
        for (int j = 0; j < 16; ++j) {
            accp[j] += fexp2(__builtin_fmaf(Ep, Lv[j], Wp));
            accn[j] += fexp2(__builtin_fmaf(En, Lv[j], Wn));
        }
    }

    // LDS diff-reduce across the 8 waves. Row stride 17 floats -> conflict-free.
    __shared__ float lds[8 * 64 * 17];   // 34816 B
    {
        const int base = ((threadIdx.x >> 6) * 64 + lane) * 17;
        #pragma unroll
        for (int j = 0; j < 16; ++j) lds[base + j] = accp[j] - accn[j];
    }
    __syncthreads();

    // 512 threads -> 1024 outputs: 2 per thread.
    {
        const int l = threadIdx.x & 63;
        #pragma unroll
        for (int r = 0; r < 2; ++r) {
            const int b = (threadIdx.x >> 6) + (r << 3);   // [0,16)
            float sum = 0.0f;
            #pragma unroll
            for (int w = 0; w < 8; ++w) sum += lds[(w * 64 + l) * 17 + b];

            // bias row (i=1024): L=1 -> term = n*g (pure mul). Added once per
            // (b,o): every (b,l) pair here is unique within the z==0 block.
            if (blockIdx.z == 0) {
                const int oo = (blockIdx.x << 6) + l;
                const float2 nb = *(const float2*)(nd + (size_t)NIN * NJ + 2 * oo);
                const float gp = __builtin_fmaf(kG, __builtin_fabsf(bp[oo]), GMIN);
                const float gn = __builtin_fmaf(kG, __builtin_fabsf(bn[oo]), GMIN);
                sum += nb.x * gp - nb.y * gn;
            }
            unsafeAtomicAdd(out + (size_t)(b0 + b) * NO + (blockIdx.x << 6) + l, C * sum);
        }
    }
}

extern "C" void kernel_launch(void* const* d_in, const int* in_sizes, int n_in,
                              void* d_out, int out_size, void* d_ws, size_t ws_size,
                              hipStream_t stream)
{
    const float* x  = (const float*)d_in[0];
    const float* wp = (const float*)d_in[1];
    const float* wn = (const float*)d_in[2];
    const float* bp = (const float*)d_in[3];
    const float* bn = (const float*)d_in[4];
    const float* nd = (const float*)d_in[5];
    float* out = (float*)d_out;

    unsigned char* ws = (unsigned char*)d_ws;
    float* bmax = (float*)ws;                 // 256 floats
    float* LT   = (float*)(ws + 4096);        // 1025*128*4 = 524800 B

    k_prep<<<256, 1024, 0, stream>>>(x, wp, wn, bp, bn, LT, bmax, out);
    k_main<<<dim3(8, 8, ZCH), 512, 0, stream>>>(nd, wp, wn, bp, bn, LT, bmax, out);
}